// Round 5
// baseline (119.628 us; speedup 1.0000x reference)
//
#include <hip/hip_runtime.h>
#include <hip/hip_fp16.h>

#define D 128
#define EPS 1e-12f

typedef float v2f __attribute__((ext_vector_type(2)));

#if defined(__has_builtin)
#if __has_builtin(__builtin_amdgcn_cvt_scalef32_pk_f32_fp4)
#define HAVE_FP4_CVT 1
#endif
#endif
#ifndef HAVE_FP4_CVT
#define HAVE_FP4_CVT 0
#endif

#if HAVE_FP4_CVT

// ---------- fp4-e2m1 table path (per-row power-of-2 scale) ----------

// e2m1 nibble encode of u in [0,6], nearest; returns 3-bit magnitude code.
__device__ __forceinline__ unsigned int e2m1_mag(float u) {
    // representable: 0, 0.5, 1, 1.5, 2, 3, 4, 6  -> codes 0..7
    if (u < 1.75f) {
        int q = (int)(u * 2.0f + 0.5f);
        return (unsigned int)q;                 // 0..3
    } else if (u < 3.5f) {
        int q = (int)(u + 0.5f);                // 2 or 3
        return (unsigned int)(q + 2);           // 4,5
    } else {
        return u < 5.0f ? 6u : 7u;              // 4 -> 6, 6 -> 7 (midpoint 5)
    }
}

// One wave per row: L1-norm + max butterflies; store x/||x||_1 as fp4 with
// per-row pow2 decode-scale S (decoded = fp4val * S). Lane i -> elems 2i,2i+1
// -> one byte (low nibble = even elem). Row = 64B, wave writes 64B coalesced.
__global__ void normalize_to_fp4_kernel(const float* __restrict__ z,
                                        float* __restrict__ scales,
                                        unsigned char* __restrict__ tab, int N) {
    int wave_in_block = threadIdx.x >> 6;
    int lane = threadIdx.x & 63;
    int row = blockIdx.x * (blockDim.x >> 6) + wave_in_block;
    if (row >= N) return;
    const float2* zp = (const float2*)(z + (size_t)row * D);
    float2 v = zp[lane];
    float ax = fabsf(v.x), ay = fabsf(v.y);
    float s = ax + ay;
    float a = fmaxf(ax, ay);
    #pragma unroll
    for (int m = 32; m >= 1; m >>= 1) {
        s += __shfl_xor(s, m, 64);
        a = fmaxf(a, __shfl_xor(a, m, 64));
    }
    float inv = 1.0f / fmaxf(s, EPS);           // 1/||x||_1
    float amax = a * inv;                       // max |normalized elem|
    // decode scale S = 2^e, smallest pow2 with 6*S >= amax
    int e;
    frexpf(fmaxf(amax, 1e-30f) * (1.0f / 6.0f), &e);  // mantissa in [0.5,1)
    float S = ldexpf(1.0f, e);
    float Sinv = ldexpf(1.0f, -e);
    if (lane == 0) scales[row] = S;
    float ux = fminf(ax * inv * Sinv, 6.0f);
    float uy = fminf(ay * inv * Sinv, 6.0f);
    unsigned int nx = e2m1_mag(ux) | (v.x < 0.0f ? 8u : 0u);
    unsigned int ny = e2m1_mag(uy) | (v.y < 0.0f ? 8u : 0u);
    tab[(size_t)row * 64 + lane] = (unsigned char)(nx | (ny << 4));
}

// Decode 8 fp4 (one uint32) with fused row scale into 8 floats.
// Byte-select operand must be a frontend constant -> explicit literals.
__device__ __forceinline__ void fp4_decode8(unsigned int w, float S, float* o) {
    v2f a = __builtin_amdgcn_cvt_scalef32_pk_f32_fp4(w, S, 0);
    v2f b = __builtin_amdgcn_cvt_scalef32_pk_f32_fp4(w, S, 1);
    v2f c = __builtin_amdgcn_cvt_scalef32_pk_f32_fp4(w, S, 2);
    v2f d = __builtin_amdgcn_cvt_scalef32_pk_f32_fp4(w, S, 3);
    o[0] = a.x; o[1] = a.y; o[2] = b.x; o[3] = b.y;
    o[4] = c.x; o[5] = c.y; o[6] = d.x; o[7] = d.y;
}

// 8 lanes per edge (8 edges/wave). Each lane: uint2 (16 fp4) per z row,
// 4x float4 of fp32 rel. HW cvt fuses the row scale. 3-step shuffle reduce.
__global__ void transe_score_fp4_kernel(const unsigned char* __restrict__ tab,
                                        const float* __restrict__ scales,
                                        const int* __restrict__ eidx,   // [2,E]
                                        const int* __restrict__ etype,  // [E]
                                        const float* __restrict__ rel,  // [R,D]
                                        float* __restrict__ out, int E) {
    int gtid = blockIdx.x * blockDim.x + threadIdx.x;
    int e = gtid >> 3;
    int lane8 = threadIdx.x & 7;
    if (e >= E) return;

    int h = eidx[e];
    int t = eidx[E + e];
    int r = etype[e];
    float sh = scales[h];
    float st = scales[t];

    uint2 hv = *(const uint2*)(tab + (size_t)h * 64 + lane8 * 8);
    uint2 tv = *(const uint2*)(tab + (size_t)t * 64 + lane8 * 8);
    const float4* rp = (const float4*)(rel + (size_t)r * D) + lane8 * 4;
    float4 r0 = rp[0], r1 = rp[1], r2 = rp[2], r3 = rp[3];
    float rf[16] = {r0.x, r0.y, r0.z, r0.w, r1.x, r1.y, r1.z, r1.w,
                    r2.x, r2.y, r2.z, r2.w, r3.x, r3.y, r3.z, r3.w};

    float hf[16], tf[16];
    fp4_decode8(hv.x, sh, hf);
    fp4_decode8(hv.y, sh, hf + 8);
    fp4_decode8(tv.x, st, tf);
    fp4_decode8(tv.y, st, tf + 8);

    float s = 0.0f;
    #pragma unroll
    for (int i = 0; i < 16; ++i)
        s += fabsf((hf[i] - tf[i]) + rf[i]);

    s += __shfl_xor(s, 1, 64);
    s += __shfl_xor(s, 2, 64);
    s += __shfl_xor(s, 4, 64);
    if (lane8 == 0) out[e] = -s;
}

#endif  // HAVE_FP4_CVT

// ---------- fp8-e4m3 path (round-3, proven; fallback) ----------

#define FP8_SCALE 64.0f
#define FP8_INV_SCALE 0.015625f

__global__ void normalize_to_fp8_kernel(const float* __restrict__ z,
                                        unsigned char* __restrict__ zn, int N) {
    int wave_in_block = threadIdx.x >> 6;
    int lane = threadIdx.x & 63;
    int row = blockIdx.x * (blockDim.x >> 6) + wave_in_block;
    if (row >= N) return;
    const float2* zp = (const float2*)(z + (size_t)row * D);
    float2 v = zp[lane];
    float s = fabsf(v.x) + fabsf(v.y);
    #pragma unroll
    for (int m = 32; m >= 1; m >>= 1)
        s += __shfl_xor(s, m, 64);
    float f = FP8_SCALE / fmaxf(s, EPS);
    int p = __builtin_amdgcn_cvt_pk_fp8_f32(v.x * f, v.y * f, 0, false);
    unsigned short* rowp = (unsigned short*)(zn + (size_t)row * D);
    rowp[lane] = (unsigned short)(p & 0xffff);
}

__global__ void transe_score_fp8_kernel(const unsigned char* __restrict__ zn,
                                        const int* __restrict__ eidx,
                                        const int* __restrict__ etype,
                                        const float* __restrict__ rel,
                                        float* __restrict__ out, int E) {
    int gtid = blockIdx.x * blockDim.x + threadIdx.x;
    int e = gtid >> 3;
    int lane8 = threadIdx.x & 7;
    if (e >= E) return;

    int h = eidx[e];
    int t = eidx[E + e];
    int r = etype[e];

    uint4 hv = ((const uint4*)(zn + (size_t)h * D))[lane8];
    uint4 tv = ((const uint4*)(zn + (size_t)t * D))[lane8];
    const float4* rp = (const float4*)(rel + (size_t)r * D) + lane8 * 4;
    float4 r0 = rp[0], r1 = rp[1], r2 = rp[2], r3 = rp[3];
    float rf[16] = {r0.x, r0.y, r0.z, r0.w, r1.x, r1.y, r1.z, r1.w,
                    r2.x, r2.y, r2.z, r2.w, r3.x, r3.y, r3.z, r3.w};

    unsigned int hw[4] = {hv.x, hv.y, hv.z, hv.w};
    unsigned int tw[4] = {tv.x, tv.y, tv.z, tv.w};

    float s = 0.0f;
    #pragma unroll
    for (int k = 0; k < 4; ++k) {
        v2f h0 = __builtin_amdgcn_cvt_pk_f32_fp8(hw[k], false);
        v2f h1 = __builtin_amdgcn_cvt_pk_f32_fp8(hw[k], true);
        v2f t0 = __builtin_amdgcn_cvt_pk_f32_fp8(tw[k], false);
        v2f t1 = __builtin_amdgcn_cvt_pk_f32_fp8(tw[k], true);
        s += fabsf(fmaf(h0.x - t0.x, FP8_INV_SCALE, rf[4 * k    ]));
        s += fabsf(fmaf(h0.y - t0.y, FP8_INV_SCALE, rf[4 * k + 1]));
        s += fabsf(fmaf(h1.x - t1.x, FP8_INV_SCALE, rf[4 * k + 2]));
        s += fabsf(fmaf(h1.y - t1.y, FP8_INV_SCALE, rf[4 * k + 3]));
    }
    s += __shfl_xor(s, 1, 64);
    s += __shfl_xor(s, 2, 64);
    s += __shfl_xor(s, 4, 64);
    if (lane8 == 0) out[e] = -s;
}

extern "C" void kernel_launch(void* const* d_in, const int* in_sizes, int n_in,
                              void* d_out, int out_size, void* d_ws, size_t ws_size,
                              hipStream_t stream) {
    const float* z    = (const float*)d_in[0];
    const int*   eidx = (const int*)d_in[1];
    const int*   etyp = (const int*)d_in[2];
    const float* rel  = (const float*)d_in[3];
    float* out = (float*)d_out;

    int N = in_sizes[0] / D;
    int E = in_sizes[2];

#if HAVE_FP4_CVT
    size_t need_fp4 = (size_t)N * 4 + (size_t)N * 64;  // scales + fp4 table
    if (ws_size >= need_fp4) {
        float* scales = (float*)d_ws;
        unsigned char* tab = (unsigned char*)d_ws + (size_t)N * 4;
        int blocks1 = (N + 3) / 4;                     // 4 waves/block, 1 row/wave
        normalize_to_fp4_kernel<<<blocks1, 256, 0, stream>>>(z, scales, tab, N);
        int blocks2 = (E + 31) / 32;                   // 32 edges / 256-thread block
        transe_score_fp4_kernel<<<blocks2, 256, 0, stream>>>(tab, scales, eidx, etyp,
                                                             rel, out, E);
        return;
    }
#endif
    {
        unsigned char* zn = (unsigned char*)d_ws;      // 12.8 MB fp8 table
        int blocks1 = (N + 3) / 4;
        normalize_to_fp8_kernel<<<blocks1, 256, 0, stream>>>(z, zn, N);
        int blocks2 = (E + 31) / 32;
        transe_score_fp8_kernel<<<blocks2, 256, 0, stream>>>(zn, eidx, etyp, rel, out, E);
    }
}

// Round 6
// 119.174 us; speedup vs baseline: 1.0038x; 1.0038x over previous
//
#include <hip/hip_runtime.h>
#include <hip/hip_fp16.h>

#define D 128
#define EPS 1e-12f

typedef float v2f __attribute__((ext_vector_type(2)));

#if defined(__has_builtin)
#if __has_builtin(__builtin_amdgcn_cvt_scalef32_pk_f32_fp4)
#define HAVE_FP4_CVT 1
#endif
#endif
#ifndef HAVE_FP4_CVT
#define HAVE_FP4_CVT 0
#endif

#if HAVE_FP4_CVT

// ---------- fp4-e2m1 z-table + fp16 rel-table path ----------

// e2m1 nibble encode of u in [0,6], nearest; returns 3-bit magnitude code.
__device__ __forceinline__ unsigned int e2m1_mag(float u) {
    // representable: 0, 0.5, 1, 1.5, 2, 3, 4, 6  -> codes 0..7
    if (u < 1.75f) {
        int q = (int)(u * 2.0f + 0.5f);
        return (unsigned int)q;                 // 0..3
    } else if (u < 3.5f) {
        int q = (int)(u + 0.5f);                // 2 or 3
        return (unsigned int)(q + 2);           // 4,5
    } else {
        return u < 5.0f ? 6u : 7u;              // 4 -> 6, 6 -> 7 (midpoint 5)
    }
}

// One wave per row. Rows [0,N): z -> L1-normalize -> fp4 + pow2 scale.
// Rows [N, N+R): rel -> fp16 copy. Lane i handles elems 2i, 2i+1.
__global__ void prep_kernel(const float* __restrict__ z,
                            const float* __restrict__ rel,
                            float* __restrict__ scales,
                            unsigned char* __restrict__ tab,
                            __half* __restrict__ rel16, int N, int R) {
    int wave_in_block = threadIdx.x >> 6;
    int lane = threadIdx.x & 63;
    int row = blockIdx.x * (blockDim.x >> 6) + wave_in_block;
    if (row < N) {
        const float2* zp = (const float2*)(z + (size_t)row * D);
        float2 v = zp[lane];
        float ax = fabsf(v.x), ay = fabsf(v.y);
        float s = ax + ay;
        float a = fmaxf(ax, ay);
        #pragma unroll
        for (int m = 32; m >= 1; m >>= 1) {
            s += __shfl_xor(s, m, 64);
            a = fmaxf(a, __shfl_xor(a, m, 64));
        }
        float inv = 1.0f / fmaxf(s, EPS);           // 1/||x||_1
        float amax = a * inv;                       // max |normalized elem|
        int e;
        frexpf(fmaxf(amax, 1e-30f) * (1.0f / 6.0f), &e);
        float S = ldexpf(1.0f, e);                  // smallest pow2 with 6S >= amax
        float Sinv = ldexpf(1.0f, -e);
        if (lane == 0) scales[row] = S;
        float ux = fminf(ax * inv * Sinv, 6.0f);
        float uy = fminf(ay * inv * Sinv, 6.0f);
        unsigned int nx = e2m1_mag(ux) | (v.x < 0.0f ? 8u : 0u);
        unsigned int ny = e2m1_mag(uy) | (v.y < 0.0f ? 8u : 0u);
        tab[(size_t)row * 64 + lane] = (unsigned char)(nx | (ny << 4));
    } else if (row < N + R) {
        int rr = row - N;
        const float2* rp = (const float2*)(rel + (size_t)rr * D);
        float2 v = rp[lane];
        ((__half2*)(rel16 + (size_t)rr * D))[lane] = __floats2half2_rn(v.x, v.y);
    }
}

// Decode 8 fp4 (one uint32) with fused row scale into 8 floats.
// Byte-select operand must be a frontend constant -> explicit literals.
__device__ __forceinline__ void fp4_decode8(unsigned int w, float S, float* o) {
    v2f a = __builtin_amdgcn_cvt_scalef32_pk_f32_fp4(w, S, 0);
    v2f b = __builtin_amdgcn_cvt_scalef32_pk_f32_fp4(w, S, 1);
    v2f c = __builtin_amdgcn_cvt_scalef32_pk_f32_fp4(w, S, 2);
    v2f d = __builtin_amdgcn_cvt_scalef32_pk_f32_fp4(w, S, 3);
    o[0] = a.x; o[1] = a.y; o[2] = b.x; o[3] = b.y;
    o[4] = c.x; o[5] = c.y; o[6] = d.x; o[7] = d.y;
}

// 8 lanes per edge (8 edges/wave). Per lane: uint2 (16 fp4) per z row,
// 2x uint4 (16 halves) of fp16 rel. 3-step shuffle reduce.
__global__ void transe_score_fp4_kernel(const unsigned char* __restrict__ tab,
                                        const float* __restrict__ scales,
                                        const int* __restrict__ eidx,     // [2,E]
                                        const int* __restrict__ etype,    // [E]
                                        const __half* __restrict__ rel16, // [R,D]
                                        float* __restrict__ out, int E) {
    int gtid = blockIdx.x * blockDim.x + threadIdx.x;
    int e = gtid >> 3;
    int lane8 = threadIdx.x & 7;
    if (e >= E) return;

    int h = eidx[e];
    int t = eidx[E + e];
    int r = etype[e];
    float sh = scales[h];
    float st = scales[t];

    uint2 hv = *(const uint2*)(tab + (size_t)h * 64 + lane8 * 8);
    uint2 tv = *(const uint2*)(tab + (size_t)t * 64 + lane8 * 8);
    const uint4* rp = (const uint4*)((const unsigned char*)rel16 + (size_t)r * 256)
                      + lane8 * 2;
    uint4 ra = rp[0];
    uint4 rb = rp[1];

    float rf[16];
    {
        const __half2* p0 = (const __half2*)&ra;
        const __half2* p1 = (const __half2*)&rb;
        #pragma unroll
        for (int i = 0; i < 4; ++i) {
            float2 f = __half22float2(p0[i]);
            rf[2 * i] = f.x; rf[2 * i + 1] = f.y;
        }
        #pragma unroll
        for (int i = 0; i < 4; ++i) {
            float2 f = __half22float2(p1[i]);
            rf[8 + 2 * i] = f.x; rf[8 + 2 * i + 1] = f.y;
        }
    }

    float hf[16], tf[16];
    fp4_decode8(hv.x, sh, hf);
    fp4_decode8(hv.y, sh, hf + 8);
    fp4_decode8(tv.x, st, tf);
    fp4_decode8(tv.y, st, tf + 8);

    float s = 0.0f;
    #pragma unroll
    for (int i = 0; i < 16; ++i)
        s += fabsf((hf[i] - tf[i]) + rf[i]);

    s += __shfl_xor(s, 1, 64);
    s += __shfl_xor(s, 2, 64);
    s += __shfl_xor(s, 4, 64);
    if (lane8 == 0) out[e] = -s;
}

#endif  // HAVE_FP4_CVT

// ---------- fp8-e4m3 path (round-3, proven; fallback) ----------

#define FP8_SCALE 64.0f
#define FP8_INV_SCALE 0.015625f

__global__ void normalize_to_fp8_kernel(const float* __restrict__ z,
                                        unsigned char* __restrict__ zn, int N) {
    int wave_in_block = threadIdx.x >> 6;
    int lane = threadIdx.x & 63;
    int row = blockIdx.x * (blockDim.x >> 6) + wave_in_block;
    if (row >= N) return;
    const float2* zp = (const float2*)(z + (size_t)row * D);
    float2 v = zp[lane];
    float s = fabsf(v.x) + fabsf(v.y);
    #pragma unroll
    for (int m = 32; m >= 1; m >>= 1)
        s += __shfl_xor(s, m, 64);
    float f = FP8_SCALE / fmaxf(s, EPS);
    int p = __builtin_amdgcn_cvt_pk_fp8_f32(v.x * f, v.y * f, 0, false);
    unsigned short* rowp = (unsigned short*)(zn + (size_t)row * D);
    rowp[lane] = (unsigned short)(p & 0xffff);
}

__global__ void transe_score_fp8_kernel(const unsigned char* __restrict__ zn,
                                        const int* __restrict__ eidx,
                                        const int* __restrict__ etype,
                                        const float* __restrict__ rel,
                                        float* __restrict__ out, int E) {
    int gtid = blockIdx.x * blockDim.x + threadIdx.x;
    int e = gtid >> 3;
    int lane8 = threadIdx.x & 7;
    if (e >= E) return;

    int h = eidx[e];
    int t = eidx[E + e];
    int r = etype[e];

    uint4 hv = ((const uint4*)(zn + (size_t)h * D))[lane8];
    uint4 tv = ((const uint4*)(zn + (size_t)t * D))[lane8];
    const float4* rp = (const float4*)(rel + (size_t)r * D) + lane8 * 4;
    float4 r0 = rp[0], r1 = rp[1], r2 = rp[2], r3 = rp[3];
    float rf[16] = {r0.x, r0.y, r0.z, r0.w, r1.x, r1.y, r1.z, r1.w,
                    r2.x, r2.y, r2.z, r2.w, r3.x, r3.y, r3.z, r3.w};

    unsigned int hw[4] = {hv.x, hv.y, hv.z, hv.w};
    unsigned int tw[4] = {tv.x, tv.y, tv.z, tv.w};

    float s = 0.0f;
    #pragma unroll
    for (int k = 0; k < 4; ++k) {
        v2f h0 = __builtin_amdgcn_cvt_pk_f32_fp8(hw[k], false);
        v2f h1 = __builtin_amdgcn_cvt_pk_f32_fp8(hw[k], true);
        v2f t0 = __builtin_amdgcn_cvt_pk_f32_fp8(tw[k], false);
        v2f t1 = __builtin_amdgcn_cvt_pk_f32_fp8(tw[k], true);
        s += fabsf(fmaf(h0.x - t0.x, FP8_INV_SCALE, rf[4 * k    ]));
        s += fabsf(fmaf(h0.y - t0.y, FP8_INV_SCALE, rf[4 * k + 1]));
        s += fabsf(fmaf(h1.x - t1.x, FP8_INV_SCALE, rf[4 * k + 2]));
        s += fabsf(fmaf(h1.y - t1.y, FP8_INV_SCALE, rf[4 * k + 3]));
    }
    s += __shfl_xor(s, 1, 64);
    s += __shfl_xor(s, 2, 64);
    s += __shfl_xor(s, 4, 64);
    if (lane8 == 0) out[e] = -s;
}

extern "C" void kernel_launch(void* const* d_in, const int* in_sizes, int n_in,
                              void* d_out, int out_size, void* d_ws, size_t ws_size,
                              hipStream_t stream) {
    const float* z    = (const float*)d_in[0];
    const int*   eidx = (const int*)d_in[1];
    const int*   etyp = (const int*)d_in[2];
    const float* rel  = (const float*)d_in[3];
    float* out = (float*)d_out;

    int N = in_sizes[0] / D;
    int E = in_sizes[2];
    int R = in_sizes[3] / D;

#if HAVE_FP4_CVT
    size_t need_fp4 = (size_t)N * 4            // scales
                    + (size_t)N * 64           // fp4 z table
                    + (size_t)R * D * 2;       // fp16 rel table
    if (ws_size >= need_fp4) {
        float* scales      = (float*)d_ws;
        unsigned char* tab = (unsigned char*)d_ws + (size_t)N * 4;
        __half* rel16      = (__half*)(tab + (size_t)N * 64);
        int blocks1 = (N + R + 3) / 4;                 // 4 waves/block, 1 row/wave
        prep_kernel<<<blocks1, 256, 0, stream>>>(z, rel, scales, tab, rel16, N, R);
        int blocks2 = (E + 31) / 32;                   // 32 edges / 256-thread block
        transe_score_fp4_kernel<<<blocks2, 256, 0, stream>>>(tab, scales, eidx, etyp,
                                                             rel16, out, E);
        return;
    }
#endif
    {
        unsigned char* zn = (unsigned char*)d_ws;      // 12.8 MB fp8 table
        int blocks1 = (N + 3) / 4;
        normalize_to_fp8_kernel<<<blocks1, 256, 0, stream>>>(z, zn, N);
        int blocks2 = (E + 31) / 32;
        transe_score_fp8_kernel<<<blocks2, 256, 0, stream>>>(zn, eidx, etyp, rel, out, E);
    }
}